// Round 10
// baseline (55967.145 us; speedup 1.0000x reference)
//
#include <hip/hip_runtime.h>

#define B_ 32
#define S_ 512
#define E_ 256
#define H_ 512
#define G_ 2048
#define K_ 7
#define SCOPE __HIP_MEMORY_SCOPE_AGENT

__device__ __forceinline__ float sigm(float x) { return 1.f / (1.f + expf(-x)); }

__device__ __forceinline__ float ldc(const float* p) {
    return __hip_atomic_load(p, __ATOMIC_RELAXED, SCOPE);
}
__device__ __forceinline__ void ld2c(const float* p, float& a, float& b) {
    unsigned long long v =
        __hip_atomic_load((const unsigned long long*)p, __ATOMIC_RELAXED, SCOPE);
    a = __builtin_bit_cast(float, (unsigned)v);
    b = __builtin_bit_cast(float, (unsigned)(v >> 32));
}
__device__ __forceinline__ void stg(float* p, float v) {
    __hip_atomic_store(p, v, __ATOMIC_RELAXED, SCOPE);
}

// 2-level monotonic grid barrier (validated round 9).
__device__ __forceinline__ void gbar(unsigned* bar, int tid, int wg, unsigned n) {
    __syncthreads();
    if (tid == 0) {
        int g = wg >> 5;
        unsigned* gcnt = bar + 64 + g * 32;
        unsigned* ggen = bar + 320 + g * 32;
        unsigned old = __hip_atomic_fetch_add(gcnt, 1u, __ATOMIC_RELAXED, SCOPE);
        if (old == n * 32u - 1u) {
            unsigned rold = __hip_atomic_fetch_add(bar, 1u, __ATOMIC_RELAXED, SCOPE);
            if (rold == n * 8u - 1u) {
                __hip_atomic_store(bar + 32, n, __ATOMIC_RELAXED, SCOPE);
            } else {
                while (__hip_atomic_load(bar + 32, __ATOMIC_RELAXED, SCOPE) < n)
                    __builtin_amdgcn_s_sleep(1);
            }
            __hip_atomic_store(ggen, n, __ATOMIC_RELAXED, SCOPE);
        } else {
            while (__hip_atomic_load(ggen, __ATOMIC_RELAXED, SCOPE) < n)
                __builtin_amdgcn_s_sleep(1);
        }
        asm volatile("" ::: "memory");
    }
    __syncthreads();
}

#define RED8(m) do { \
    a00 += __shfl_xor(a00, m, 64); a01 += __shfl_xor(a01, m, 64); \
    a02 += __shfl_xor(a02, m, 64); a03 += __shfl_xor(a03, m, 64); \
    a10 += __shfl_xor(a10, m, 64); a11 += __shfl_xor(a11, m, 64); \
    a12 += __shfl_xor(a12, m, 64); a13 += __shfl_xor(a13, m, 64); } while (0)

__global__ __launch_bounds__(512, 2) void fused_all(
        const int* __restrict__ x, const int* __restrict__ taskp,
        const float* __restrict__ embed,
        const float* __restrict__ Wx_t, const float* __restrict__ Wh_t,
        const float* __restrict__ b_t,
        const float* __restrict__ Ws_p1, const float* __restrict__ Ws_p2,
        const float* __restrict__ Us_w,
        const float* __restrict__ Wx_c, const float* __restrict__ Wh_c,
        const float* __restrict__ Wm_c, const float* __restrict__ b_c,
        float* __restrict__ out,
        float* __restrict__ emb_t,
        float* __restrict__ h_task, float* __restrict__ c_task,
        float* __restrict__ h_main, float* __restrict__ c_main,
        float* __restrict__ p2w, float* __restrict__ partial,
        unsigned* __restrict__ bar)
{
    __shared__ float sact[27648];   // A: [768][36]; B: [512][36]; C: [1280][4]
    __shared__ float smisc[2048];

    const int wg = blockIdx.x, tid = threadIdx.x;
    const int lane = tid & 63, wave = tid >> 6;
    const int task = taskp[0];
    unsigned bn = 0;

    // thread coords (A & C): column-pair cp (0..31), row-chunk rc (0..15)
    const int cp = wave * 4 + (lane & 3);
    const int rc = (lane >> 2) & 15;
    const int tc = 2 * cp;                 // tile col (even)

    // ---------------- prologue: zero state, emb gather+transpose ----------------
    for (int i = wg * 512 + tid; i < 393216; i += 131072)
        stg(&h_task[i], 0.f);  // h_task(2)+c_task+h_main(2)+c_main contiguous
    for (int w = wg * 2 + (tid >> 8); w < S_ * B_; w += 512) {
        int ts = w >> 5, b = w & 31;
        int tok = x[b * S_ + ts];
        stg(&emb_t[(size_t)ts * 8192 + (tid & 255) * 32 + b],
            embed[(size_t)tok * E_ + (tid & 255)]);
    }

    // ---------------- persistent register weights ----------------
    const int kA = wg >> 5, ntA = wg & 31;              // A task coords
    const int wcA = ((tc >> 4) << 9) + ntA * 16 + (tc & 15);
    float2 w2[48];
    if (wg < 224) {
        int kk = kA + (kA >= task);
#pragma unroll
        for (int i = 0; i < 48; ++i) {
            int row = i * 16 + rc;
            const float* src = (i < 16)
                ? (Wx_t + ((size_t)kk * 256 + row) * 2048 + wcA)
                : (Wh_t + ((size_t)kk * 512 + (row - 256)) * 2048 + wcA);
            w2[i] = *(const float2*)src;
        }
    } else if (wg < 232) {
        int wcP = (wg - 224) * 64 + tc;
#pragma unroll
        for (int i = 0; i < 48; ++i)
            w2[i] = *(const float2*)(Ws_p2 + (size_t)(i * 16 + rc) * 512 + wcP);
    }
    // B coords + weights: WG (kt, it) = (wg>>5, wg&31); thread (c,rcB,bh)
    const int cB = tid & 15, rcB = (tid >> 4) & 15, bhB = tid >> 8;
    float w1[32];
    if (wg < 224) {
        int colB = (wg & 31) * 16 + cB;
#pragma unroll
        for (int i = 0; i < 32; ++i)
            w1[i] = Ws_p1[(size_t)colB * 512 + i * 16 + rcB];
    }
    gbar(bar, tid, wg, ++bn);

    for (int t = 0; t < S_; ++t) {
        const int old = t & 1, nw = old ^ 1;
        float* ht_old = h_task + (size_t)old * K_ * B_ * H_;
        float* ht_new = h_task + (size_t)nw * K_ * B_ * H_;
        float* hm_old = h_main + (size_t)old * B_ * H_;
        float* hm_new = h_main + (size_t)nw * B_ * H_;

        // ================= Phase A: task gates+cell (wg<224) + p2 (224..231) =====
        if (wg < 232) {
            const bool istask = wg < 224;
            if (istask) {
                for (int j = 0; j < 8; ++j) {        // emb rows 0..255
                    int idx = tid + 512 * j;
                    int rho = idx >> 4, b2 = (idx & 15) << 1;
                    *(float2*)(sact + rho * 36 + b2) =
                        *(const float2*)(emb_t + (size_t)t * 8192 + rho * 32 + b2);
                }
                for (int j = 0; j < 16; ++j) {       // h rows 256..767
                    int idx = tid + 512 * j;
                    int b = idx & 31, rp = idx >> 5;
                    float va, vb;
                    ld2c(&ht_old[((size_t)kA * 32 + b) * 512 + 2 * rp], va, vb);
                    sact[(256 + 2 * rp) * 36 + b] = va;
                    sact[(257 + 2 * rp) * 36 + b] = vb;
                }
            } else {
                for (int j = 0; j < 16; ++j) {       // hm rows 0..511
                    int idx = tid + 512 * j;
                    int b = idx & 31, rp = idx >> 5;
                    float va, vb;
                    ld2c(&hm_old[(size_t)b * 512 + 2 * rp], va, vb);
                    sact[(2 * rp) * 36 + b] = va;
                    sact[(2 * rp + 1) * 36 + b] = vb;
                }
                for (int j = 0; j < 8; ++j) {        // emb rows 512..767
                    int idx = tid + 512 * j;
                    int rho = idx >> 4, b2 = (idx & 15) << 1;
                    *(float2*)(sact + (512 + rho) * 36 + b2) =
                        *(const float2*)(emb_t + (size_t)t * 8192 + rho * 32 + b2);
                }
            }
            __syncthreads();
            for (int bg = 0; bg < 8; ++bg) {
                float a00 = 0, a01 = 0, a02 = 0, a03 = 0;
                float a10 = 0, a11 = 0, a12 = 0, a13 = 0;
                const float* ap = sact + rc * 36 + 4 * bg;
#pragma unroll
                for (int i = 0; i < 48; ++i) {
                    float4 av = *(const float4*)(ap + i * 576);
                    a00 = fmaf(w2[i].x, av.x, a00); a01 = fmaf(w2[i].x, av.y, a01);
                    a02 = fmaf(w2[i].x, av.z, a02); a03 = fmaf(w2[i].x, av.w, a03);
                    a10 = fmaf(w2[i].y, av.x, a10); a11 = fmaf(w2[i].y, av.y, a11);
                    a12 = fmaf(w2[i].y, av.z, a12); a13 = fmaf(w2[i].y, av.w, a13);
                }
                RED8(4); RED8(8); RED8(16); RED8(32);
                if (rc == 0) {
                    smisc[(4 * bg + 0) * 64 + tc] = a00; smisc[(4 * bg + 0) * 64 + tc + 1] = a10;
                    smisc[(4 * bg + 1) * 64 + tc] = a01; smisc[(4 * bg + 1) * 64 + tc + 1] = a11;
                    smisc[(4 * bg + 2) * 64 + tc] = a02; smisc[(4 * bg + 2) * 64 + tc + 1] = a12;
                    smisc[(4 * bg + 3) * 64 + tc] = a03; smisc[(4 * bg + 3) * 64 + tc + 1] = a13;
                }
            }
            __syncthreads();
            if (istask) {
                int kk = kA + (kA >= task);
                int b = tid >> 4, hc = tid & 15;
                const float* bb = b_t + kk * G_ + ntA * 16 + hc;
                float gi = smisc[b * 64 + hc]      + bb[0];
                float gf = smisc[b * 64 + 16 + hc] + bb[512];
                float gg = smisc[b * 64 + 32 + hc] + bb[1024];
                float go = smisc[b * 64 + 48 + hc] + bb[1536];
                size_t cidx = ((size_t)kA * 32 + b) * 512 + ntA * 16 + hc;
                float cold = c_task[cidx];
                float cn = sigm(gf) * cold + sigm(gi) * tanhf(gg);
                float hn = sigm(go) * tanhf(cn);
                c_task[cidx] = cn;
                stg(&ht_new[cidx], hn);
            } else {
                int pb = wg - 224;
                for (int j = 0; j < 4; ++j) {
                    int idx = tid + 512 * j;
                    int b = idx >> 6, col = idx & 63;
                    stg(&p2w[(size_t)b * 512 + pb * 64 + col], smisc[b * 64 + col]);
                }
            }
        }
        gbar(bar, tid, wg, ++bn);

        // ================= Phase B: attention partials (wg<224) =================
        if (wg < 224) {
            const int ktB = wg >> 5, itB = wg & 31;
            for (int j = 0; j < 16; ++j) {
                int idx = tid + 512 * j;
                int b = idx & 31, rp = idx >> 5;
                float va, vb;
                ld2c(&ht_new[((size_t)ktB * 32 + b) * 512 + 2 * rp], va, vb);
                sact[(2 * rp) * 36 + b] = va;
                sact[(2 * rp + 1) * 36 + b] = vb;
            }
            __syncthreads();
            for (int bg = 0; bg < 4; ++bg) {
                float c0 = 0, c1 = 0, c2 = 0, c3 = 0;
                const float* ap = sact + rcB * 36 + bhB * 16 + 4 * bg;
#pragma unroll
                for (int i = 0; i < 32; ++i) {
                    float4 av = *(const float4*)(ap + i * 576);
                    c0 = fmaf(w1[i], av.x, c0); c1 = fmaf(w1[i], av.y, c1);
                    c2 = fmaf(w1[i], av.z, c2); c3 = fmaf(w1[i], av.w, c3);
                }
                c0 += __shfl_xor(c0, 16, 64); c0 += __shfl_xor(c0, 32, 64);
                c1 += __shfl_xor(c1, 16, 64); c1 += __shfl_xor(c1, 32, 64);
                c2 += __shfl_xor(c2, 16, 64); c2 += __shfl_xor(c2, 32, 64);
                c3 += __shfl_xor(c3, 16, 64); c3 += __shfl_xor(c3, 32, 64);
                if ((rcB & 3) == 0) {
                    int pp = rcB >> 2;
                    int bb0 = bhB * 16 + bg * 4;
                    smisc[pp * 512 + (bb0 + 0) * 16 + cB] = c0;
                    smisc[pp * 512 + (bb0 + 1) * 16 + cB] = c1;
                    smisc[pp * 512 + (bb0 + 2) * 16 + cB] = c2;
                    smisc[pp * 512 + (bb0 + 3) * 16 + cB] = c3;
                }
            }
            __syncthreads();
            {
                int b = tid >> 4, c = tid & 15;
                float s = smisc[b * 16 + c] + smisc[512 + b * 16 + c]
                        + smisc[1024 + b * 16 + c] + smisc[1536 + b * 16 + c];
                s = tanhf(s + ldc(&p2w[(size_t)b * 512 + itB * 16 + c]))
                    * Us_w[itB * 16 + c];
                s += __shfl_xor(s, 1, 64); s += __shfl_xor(s, 2, 64);
                s += __shfl_xor(s, 4, 64); s += __shfl_xor(s, 8, 64);
                if (c == 0) stg(&partial[((size_t)ktB * 32 + itB) * 32 + b], s);
            }
        }
        gbar(bar, tid, wg, ++bn);

        // ================= Phase C: softmax + Rt + main gates + cell ============
        {
            const int ntC = wg >> 3, btC = wg & 7;   // nt-major: XCD-local weights
            const int wcC = ((tc >> 4) << 9) + ntC * 16 + (tc & 15);
            float* ssi = smisc;          // 28
            float* sa  = smisc + 32;     // 28
            float* sgt = smisc + 64;     // 4*64
            if (tid < 28) {
                int kq = tid >> 2, b2 = tid & 3;
                float ssum = 0.f;
                for (int itq = 0; itq < 32; ++itq)
                    ssum += ldc(&partial[((size_t)kq * 32 + itq) * 32 + 4 * btC + b2]);
                ssi[b2 * 7 + kq] = ssum;
            }
            __syncthreads();
            if (tid < 4) {
                float mx = -1e30f;
                for (int kq = 0; kq < 7; ++kq) mx = fmaxf(mx, ssi[tid * 7 + kq]);
                float den = 0.f, e[7];
                for (int kq = 0; kq < 7; ++kq) { e[kq] = expf(ssi[tid * 7 + kq] - mx); den += e[kq]; }
                float rd = 1.f / den;
                for (int kq = 0; kq < 7; ++kq) sa[tid * 7 + kq] = e[kq] * rd;
            }
            if (tid < 256)                            // emb rows 0..255
                *(float4*)(sact + tid * 4) =
                    *(const float4*)(emb_t + (size_t)t * 8192 + tid * 32 + 4 * btC);
            for (int j = 0; j < 2; ++j) {             // hm rows 256..767
                int idx = tid + 512 * j;
                int bl = idx & 3, rp = idx >> 2;
                float va, vb;
                ld2c(&hm_old[(size_t)(4 * btC + bl) * 512 + 2 * rp], va, vb);
                sact[(256 + 2 * rp) * 4 + bl] = va;
                sact[(257 + 2 * rp) * 4 + bl] = vb;
            }
            __syncthreads();                          // sa ready
            for (int j = 0; j < 2; ++j) {             // Rt rows 768..1279
                int idx = tid + 512 * j;
                int bl = idx & 3, rp = idx >> 2;
                float v0 = 0.f, v1 = 0.f;
#pragma unroll
                for (int kq = 0; kq < 7; ++kq) {
                    float ha, hb;
                    ld2c(&ht_new[((size_t)kq * 32 + 4 * btC + bl) * 512 + 2 * rp], ha, hb);
                    float aq = sa[bl * 7 + kq];
                    v0 = fmaf(aq, ha, v0);
                    v1 = fmaf(aq, hb, v1);
                }
                sact[(768 + 2 * rp) * 4 + bl] = v0;
                sact[(769 + 2 * rp) * 4 + bl] = v1;
            }
            __syncthreads();
            float a00 = 0, a01 = 0, a02 = 0, a03 = 0;
            float a10 = 0, a11 = 0, a12 = 0, a13 = 0;
            const float* ap = sact + rc * 4;
#pragma unroll
            for (int i = 0; i < 80; ++i) {
                int row = i * 16 + rc;
                const float* wsrc = (i < 16)
                    ? (Wx_c + (size_t)row * 2048 + wcC)
                    : (i < 48) ? (Wh_c + (size_t)(row - 256) * 2048 + wcC)
                               : (Wm_c + (size_t)(row - 768) * 2048 + wcC);
                float2 w = *(const float2*)wsrc;
                float4 av = *(const float4*)(ap + i * 64);
                a00 = fmaf(w.x, av.x, a00); a01 = fmaf(w.x, av.y, a01);
                a02 = fmaf(w.x, av.z, a02); a03 = fmaf(w.x, av.w, a03);
                a10 = fmaf(w.y, av.x, a10); a11 = fmaf(w.y, av.y, a11);
                a12 = fmaf(w.y, av.z, a12); a13 = fmaf(w.y, av.w, a13);
            }
            RED8(4); RED8(8); RED8(16); RED8(32);
            if (rc == 0) {
                sgt[0 * 64 + tc] = a00; sgt[0 * 64 + tc + 1] = a10;
                sgt[1 * 64 + tc] = a01; sgt[1 * 64 + tc + 1] = a11;
                sgt[2 * 64 + tc] = a02; sgt[2 * 64 + tc + 1] = a12;
                sgt[3 * 64 + tc] = a03; sgt[3 * 64 + tc + 1] = a13;
            }
            __syncthreads();
            if (tid < 64) {
                int bl = tid >> 4, hc = tid & 15;
                int gb = 4 * btC + bl;
                float g4[4];
#pragma unroll
                for (int g = 0; g < 4; ++g)
                    g4[g] = sgt[bl * 64 + g * 16 + hc] + b_c[g * 512 + ntC * 16 + hc];
                size_t cidx = (size_t)gb * 512 + ntC * 16 + hc;
                float cold = c_main[cidx];
                float cn = sigm(g4[1]) * cold + sigm(g4[0]) * tanhf(g4[2]);
                float hn = sigm(g4[3]) * tanhf(cn);
                c_main[cidx] = cn;
                stg(&hm_new[cidx], hn);
                out[(size_t)gb * S_ * H_ + (size_t)t * 512 + ntC * 16 + hc] = hn;
            }
        }
        gbar(bar, tid, wg, ++bn);
    }

    for (int i = wg * 512 + tid; i < B_ * H_; i += 131072)
        out[(size_t)B_ * S_ * H_ + i] = ldc(&h_main[i]);
}

extern "C" void kernel_launch(void* const* d_in, const int* in_sizes, int n_in,
                              void* d_out, int out_size, void* d_ws, size_t ws_size,
                              hipStream_t stream) {
    const int*   x      = (const int*)d_in[0];
    const int*   taskp  = (const int*)d_in[1];
    const float* embed  = (const float*)d_in[2];
    const float* Wx_t   = (const float*)d_in[3];
    const float* Wh_t   = (const float*)d_in[4];
    const float* b_t    = (const float*)d_in[5];
    const float* Ws_p1  = (const float*)d_in[6];
    const float* Ws_p2  = (const float*)d_in[7];
    const float* Us_w   = (const float*)d_in[8];
    const float* Wx_c   = (const float*)d_in[10];
    const float* Wh_c   = (const float*)d_in[11];
    const float* Wm_c   = (const float*)d_in[12];
    const float* b_c    = (const float*)d_in[13];
    float* out = (float*)d_out;

    float* ws = (float*)d_ws;
    float* emb_t   = ws;                                  // S*E*B   = 4,194,304 ([t][e][b])
    float* h_task  = emb_t   + (size_t)S_ * E_ * B_;      // 2*K*B*H =   229,376
    float* c_task  = h_task  + 2 * (size_t)K_ * B_ * H_;  // K*B*H   =   114,688
    float* h_main  = c_task  + (size_t)K_ * B_ * H_;      // 2*B*H   =    32,768
    float* c_main  = h_main  + 2 * (size_t)B_ * H_;       // B*H     =    16,384
    float* p2      = c_main  + (size_t)B_ * H_;           // B*H     =    16,384
    float* partial = p2      + (size_t)B_ * H_;           // K*32*32 =     7,168
    unsigned* bar  = (unsigned*)(partial + 7168);         // 2-level barrier state

    hipMemsetAsync(bar, 0, 4096, stream);

    void* args[] = { (void*)&x, (void*)&taskp, (void*)&embed,
                     (void*)&Wx_t, (void*)&Wh_t, (void*)&b_t,
                     (void*)&Ws_p1, (void*)&Ws_p2, (void*)&Us_w,
                     (void*)&Wx_c, (void*)&Wh_c, (void*)&Wm_c, (void*)&b_c,
                     (void*)&out,
                     (void*)&emb_t, (void*)&h_task, (void*)&c_task,
                     (void*)&h_main, (void*)&c_main, (void*)&p2, (void*)&partial,
                     (void*)&bar };
    hipLaunchCooperativeKernel((void*)fused_all, dim3(256), dim3(512), args, 0, stream);
}

// Round 11
// 50395.480 us; speedup vs baseline: 1.1106x; 1.1106x over previous
//
#include <hip/hip_runtime.h>

#define B_ 32
#define S_ 512
#define E_ 256
#define H_ 512
#define G_ 2048
#define K_ 7
#define SCOPE __HIP_MEMORY_SCOPE_AGENT

__device__ __forceinline__ float sigm(float x) { return 1.f / (1.f + expf(-x)); }

__device__ __forceinline__ float ldc(const float* p) {
    return __hip_atomic_load(p, __ATOMIC_RELAXED, SCOPE);
}
__device__ __forceinline__ void ld2c(const float* p, float& a, float& b) {
    unsigned long long v =
        __hip_atomic_load((const unsigned long long*)p, __ATOMIC_RELAXED, SCOPE);
    a = __builtin_bit_cast(float, (unsigned)v);
    b = __builtin_bit_cast(float, (unsigned)(v >> 32));
}
__device__ __forceinline__ void stg(float* p, float v) {
    __hip_atomic_store(p, v, __ATOMIC_RELAXED, SCOPE);
}

// 2-level monotonic grid barrier (validated round 9).
__device__ __forceinline__ void gbar(unsigned* bar, int tid, int wg, unsigned n) {
    __syncthreads();
    if (tid == 0) {
        int g = wg >> 5;
        unsigned* gcnt = bar + 64 + g * 32;
        unsigned* ggen = bar + 320 + g * 32;
        unsigned old = __hip_atomic_fetch_add(gcnt, 1u, __ATOMIC_RELAXED, SCOPE);
        if (old == n * 32u - 1u) {
            unsigned rold = __hip_atomic_fetch_add(bar, 1u, __ATOMIC_RELAXED, SCOPE);
            if (rold == n * 8u - 1u) {
                __hip_atomic_store(bar + 32, n, __ATOMIC_RELAXED, SCOPE);
            } else {
                while (__hip_atomic_load(bar + 32, __ATOMIC_RELAXED, SCOPE) < n)
                    __builtin_amdgcn_s_sleep(1);
            }
            __hip_atomic_store(ggen, n, __ATOMIC_RELAXED, SCOPE);
        } else {
            while (__hip_atomic_load(ggen, __ATOMIC_RELAXED, SCOPE) < n)
                __builtin_amdgcn_s_sleep(1);
        }
        asm volatile("" ::: "memory");
    }
    __syncthreads();
}

#define RED8(m) do { \
    a00 += __shfl_xor(a00, m, 64); a01 += __shfl_xor(a01, m, 64); \
    a02 += __shfl_xor(a02, m, 64); a03 += __shfl_xor(a03, m, 64); \
    a10 += __shfl_xor(a10, m, 64); a11 += __shfl_xor(a11, m, 64); \
    a12 += __shfl_xor(a12, m, 64); a13 += __shfl_xor(a13, m, 64); } while (0)

__global__ __launch_bounds__(512, 1) void fused_all(
        const int* __restrict__ x, const int* __restrict__ taskp,
        const float* __restrict__ embed,
        const float* __restrict__ Wx_t, const float* __restrict__ Wh_t,
        const float* __restrict__ b_t,
        const float* __restrict__ Ws_p1, const float* __restrict__ Ws_p2,
        const float* __restrict__ Us_w,
        const float* __restrict__ Wx_c, const float* __restrict__ Wh_c,
        const float* __restrict__ Wm_c, const float* __restrict__ b_c,
        float* __restrict__ out,
        float* __restrict__ emb_t,
        float* __restrict__ h_task, float* __restrict__ c_task,
        float* __restrict__ h_main, float* __restrict__ c_main,
        float* __restrict__ p2w, float* __restrict__ partial,
        unsigned* __restrict__ bar)
{
    __shared__ float sact[27648];   // A: [768][36]; B: [512][36]; C: [1280][4]
    __shared__ float smisc[2048];

    const int wg = blockIdx.x, tid = threadIdx.x;
    const int lane = tid & 63, wave = tid >> 6;
    const int task = taskp[0];
    unsigned bn = 0;

    // thread coords (A & C): column-pair cp (0..31), row-chunk rc (0..15)
    const int cp = wave * 4 + (lane & 3);
    const int rc = (lane >> 2) & 15;
    const int tc = 2 * cp;                 // tile col (even)

    // ---------------- prologue: zero state, emb gather+transpose ----------------
    for (int i = wg * 512 + tid; i < 393216; i += 131072)
        stg(&h_task[i], 0.f);  // h_task(2)+c_task+h_main(2)+c_main contiguous
    for (int w = wg * 2 + (tid >> 8); w < S_ * B_; w += 512) {
        int ts = w >> 5, b = w & 31;
        int tok = x[b * S_ + ts];
        stg(&emb_t[(size_t)ts * 8192 + (tid & 255) * 32 + b],
            embed[(size_t)tok * E_ + (tid & 255)]);
    }

    // ---------------- persistent register weights ----------------
    const int kA = wg >> 5, ntA = wg & 31;              // A task coords
    const int wcA = ((tc >> 4) << 9) + ntA * 16 + (tc & 15);
    float2 w2[48];
    if (wg < 224) {
        int kk = kA + (kA >= task);
#pragma unroll
        for (int i = 0; i < 48; ++i) {
            int row = i * 16 + rc;
            const float* src = (i < 16)
                ? (Wx_t + ((size_t)kk * 256 + row) * 2048 + wcA)
                : (Wh_t + ((size_t)kk * 512 + (row - 256)) * 2048 + wcA);
            w2[i] = *(const float2*)src;
        }
    } else if (wg < 232) {
        int wcP = (wg - 224) * 64 + tc;
#pragma unroll
        for (int i = 0; i < 48; ++i)
            w2[i] = *(const float2*)(Ws_p2 + (size_t)(i * 16 + rc) * 512 + wcP);
    }
    // B coords + weights: WG (kt, it) = (wg>>5, wg&31); thread (c,rcB,bh)
    const int cB = tid & 15, rcB = (tid >> 4) & 15, bhB = tid >> 8;
    float w1[32];
    if (wg < 224) {
        int colB = (wg & 31) * 16 + cB;
#pragma unroll
        for (int i = 0; i < 32; ++i)
            w1[i] = Ws_p1[(size_t)colB * 512 + i * 16 + rcB];
    }
    gbar(bar, tid, wg, ++bn);

    for (int t = 0; t < S_; ++t) {
        const int old = t & 1, nw = old ^ 1;
        float* ht_old = h_task + (size_t)old * K_ * B_ * H_;
        float* ht_new = h_task + (size_t)nw * K_ * B_ * H_;
        float* hm_old = h_main + (size_t)old * B_ * H_;
        float* hm_new = h_main + (size_t)nw * B_ * H_;

        // ================= Phase A: task gates+cell (wg<224) + p2 (224..231) =====
        if (wg < 232) {
            const bool istask = wg < 224;
            if (istask) {
                for (int j = 0; j < 8; ++j) {        // emb rows 0..255
                    int idx = tid + 512 * j;
                    int rho = idx >> 4, b2 = (idx & 15) << 1;
                    *(float2*)(sact + rho * 36 + b2) =
                        *(const float2*)(emb_t + (size_t)t * 8192 + rho * 32 + b2);
                }
                for (int j = 0; j < 16; ++j) {       // h rows 256..767
                    int idx = tid + 512 * j;
                    int b = idx & 31, rp = idx >> 5;
                    float va, vb;
                    ld2c(&ht_old[((size_t)kA * 32 + b) * 512 + 2 * rp], va, vb);
                    sact[(256 + 2 * rp) * 36 + b] = va;
                    sact[(257 + 2 * rp) * 36 + b] = vb;
                }
            } else {
                for (int j = 0; j < 16; ++j) {       // hm rows 0..511
                    int idx = tid + 512 * j;
                    int b = idx & 31, rp = idx >> 5;
                    float va, vb;
                    ld2c(&hm_old[(size_t)b * 512 + 2 * rp], va, vb);
                    sact[(2 * rp) * 36 + b] = va;
                    sact[(2 * rp + 1) * 36 + b] = vb;
                }
                for (int j = 0; j < 8; ++j) {        // emb rows 512..767
                    int idx = tid + 512 * j;
                    int rho = idx >> 4, b2 = (idx & 15) << 1;
                    *(float2*)(sact + (512 + rho) * 36 + b2) =
                        *(const float2*)(emb_t + (size_t)t * 8192 + rho * 32 + b2);
                }
            }
            __syncthreads();
            for (int bg = 0; bg < 8; ++bg) {
                float a00 = 0, a01 = 0, a02 = 0, a03 = 0;
                float a10 = 0, a11 = 0, a12 = 0, a13 = 0;
                const float* ap = sact + rc * 36 + 4 * bg;
#pragma unroll
                for (int i = 0; i < 48; ++i) {
                    float4 av = *(const float4*)(ap + i * 576);
                    a00 = fmaf(w2[i].x, av.x, a00); a01 = fmaf(w2[i].x, av.y, a01);
                    a02 = fmaf(w2[i].x, av.z, a02); a03 = fmaf(w2[i].x, av.w, a03);
                    a10 = fmaf(w2[i].y, av.x, a10); a11 = fmaf(w2[i].y, av.y, a11);
                    a12 = fmaf(w2[i].y, av.z, a12); a13 = fmaf(w2[i].y, av.w, a13);
                }
                RED8(4); RED8(8); RED8(16); RED8(32);
                if (rc == 0) {
                    smisc[(4 * bg + 0) * 64 + tc] = a00; smisc[(4 * bg + 0) * 64 + tc + 1] = a10;
                    smisc[(4 * bg + 1) * 64 + tc] = a01; smisc[(4 * bg + 1) * 64 + tc + 1] = a11;
                    smisc[(4 * bg + 2) * 64 + tc] = a02; smisc[(4 * bg + 2) * 64 + tc + 1] = a12;
                    smisc[(4 * bg + 3) * 64 + tc] = a03; smisc[(4 * bg + 3) * 64 + tc + 1] = a13;
                }
            }
            __syncthreads();
            if (istask) {
                int kk = kA + (kA >= task);
                int b = tid >> 4, hc = tid & 15;
                const float* bb = b_t + kk * G_ + ntA * 16 + hc;
                float gi = smisc[b * 64 + hc]      + bb[0];
                float gf = smisc[b * 64 + 16 + hc] + bb[512];
                float gg = smisc[b * 64 + 32 + hc] + bb[1024];
                float go = smisc[b * 64 + 48 + hc] + bb[1536];
                size_t cidx = ((size_t)kA * 32 + b) * 512 + ntA * 16 + hc;
                float cold = c_task[cidx];
                float cn = sigm(gf) * cold + sigm(gi) * tanhf(gg);
                float hn = sigm(go) * tanhf(cn);
                c_task[cidx] = cn;
                stg(&ht_new[cidx], hn);
            } else {
                int pb = wg - 224;
                for (int j = 0; j < 4; ++j) {
                    int idx = tid + 512 * j;
                    int b = idx >> 6, col = idx & 63;
                    stg(&p2w[(size_t)b * 512 + pb * 64 + col], smisc[b * 64 + col]);
                }
            }
        }
        gbar(bar, tid, wg, ++bn);

        // ================= Phase B: attention partials (wg<224) =================
        if (wg < 224) {
            const int ktB = wg >> 5, itB = wg & 31;
            for (int j = 0; j < 16; ++j) {
                int idx = tid + 512 * j;
                int b = idx & 31, rp = idx >> 5;
                float va, vb;
                ld2c(&ht_new[((size_t)ktB * 32 + b) * 512 + 2 * rp], va, vb);
                sact[(2 * rp) * 36 + b] = va;
                sact[(2 * rp + 1) * 36 + b] = vb;
            }
            __syncthreads();
            for (int bg = 0; bg < 4; ++bg) {
                float c0 = 0, c1 = 0, c2 = 0, c3 = 0;
                const float* ap = sact + rcB * 36 + bhB * 16 + 4 * bg;
#pragma unroll
                for (int i = 0; i < 32; ++i) {
                    float4 av = *(const float4*)(ap + i * 576);
                    c0 = fmaf(w1[i], av.x, c0); c1 = fmaf(w1[i], av.y, c1);
                    c2 = fmaf(w1[i], av.z, c2); c3 = fmaf(w1[i], av.w, c3);
                }
                c0 += __shfl_xor(c0, 16, 64); c0 += __shfl_xor(c0, 32, 64);
                c1 += __shfl_xor(c1, 16, 64); c1 += __shfl_xor(c1, 32, 64);
                c2 += __shfl_xor(c2, 16, 64); c2 += __shfl_xor(c2, 32, 64);
                c3 += __shfl_xor(c3, 16, 64); c3 += __shfl_xor(c3, 32, 64);
                if ((rcB & 3) == 0) {
                    int pp = rcB >> 2;
                    int bb0 = bhB * 16 + bg * 4;
                    smisc[pp * 512 + (bb0 + 0) * 16 + cB] = c0;
                    smisc[pp * 512 + (bb0 + 1) * 16 + cB] = c1;
                    smisc[pp * 512 + (bb0 + 2) * 16 + cB] = c2;
                    smisc[pp * 512 + (bb0 + 3) * 16 + cB] = c3;
                }
            }
            __syncthreads();
            {
                int b = tid >> 4, c = tid & 15;
                float s = smisc[b * 16 + c] + smisc[512 + b * 16 + c]
                        + smisc[1024 + b * 16 + c] + smisc[1536 + b * 16 + c];
                s = tanhf(s + ldc(&p2w[(size_t)b * 512 + itB * 16 + c]))
                    * Us_w[itB * 16 + c];
                s += __shfl_xor(s, 1, 64); s += __shfl_xor(s, 2, 64);
                s += __shfl_xor(s, 4, 64); s += __shfl_xor(s, 8, 64);
                if (c == 0) stg(&partial[((size_t)ktB * 32 + itB) * 32 + b], s);
            }
        }
        gbar(bar, tid, wg, ++bn);

        // ================= Phase C: softmax + Rt + main gates + cell ============
        {
            // XCD-aware decode: sharers of one ntC weight slice have equal wg%8
            // (round-robin wg->XCD) -> slice lives in ONE XCD's L2, 1.3 MB/XCD.
            const int ntC = ((wg >> 6) << 3) + (wg & 7);
            const int btC = (wg >> 3) & 7;
            const int wcC = ((tc >> 4) << 9) + ntC * 16 + (tc & 15);
            float* ssi = smisc;          // 28
            float* sa  = smisc + 32;     // 28
            float* sgt = smisc + 64;     // 4*64
            if (tid < 28) {
                int kq = tid >> 2, b2 = tid & 3;
                float ssum = 0.f;
                for (int itq = 0; itq < 32; ++itq)
                    ssum += ldc(&partial[((size_t)kq * 32 + itq) * 32 + 4 * btC + b2]);
                ssi[b2 * 7 + kq] = ssum;
            }
            __syncthreads();
            if (tid < 4) {
                float mx = -1e30f;
                for (int kq = 0; kq < 7; ++kq) mx = fmaxf(mx, ssi[tid * 7 + kq]);
                float den = 0.f, e[7];
                for (int kq = 0; kq < 7; ++kq) { e[kq] = expf(ssi[tid * 7 + kq] - mx); den += e[kq]; }
                float rd = 1.f / den;
                for (int kq = 0; kq < 7; ++kq) sa[tid * 7 + kq] = e[kq] * rd;
            }
            if (tid < 256)                            // emb rows 0..255
                *(float4*)(sact + tid * 4) =
                    *(const float4*)(emb_t + (size_t)t * 8192 + tid * 32 + 4 * btC);
            for (int j = 0; j < 2; ++j) {             // hm rows 256..767
                int idx = tid + 512 * j;
                int bl = idx & 3, rp = idx >> 2;
                float va, vb;
                ld2c(&hm_old[(size_t)(4 * btC + bl) * 512 + 2 * rp], va, vb);
                sact[(256 + 2 * rp) * 4 + bl] = va;
                sact[(257 + 2 * rp) * 4 + bl] = vb;
            }
            __syncthreads();                          // sa ready
            for (int j = 0; j < 2; ++j) {             // Rt rows 768..1279
                int idx = tid + 512 * j;
                int bl = idx & 3, rp = idx >> 2;
                float v0 = 0.f, v1 = 0.f;
#pragma unroll
                for (int kq = 0; kq < 7; ++kq) {
                    float ha, hb;
                    ld2c(&ht_new[((size_t)kq * 32 + 4 * btC + bl) * 512 + 2 * rp], ha, hb);
                    float aq = sa[bl * 7 + kq];
                    v0 = fmaf(aq, ha, v0);
                    v1 = fmaf(aq, hb, v1);
                }
                sact[(768 + 2 * rp) * 4 + bl] = v0;
                sact[(769 + 2 * rp) * 4 + bl] = v1;
            }
            __syncthreads();
            float a00 = 0, a01 = 0, a02 = 0, a03 = 0;
            float a10 = 0, a11 = 0, a12 = 0, a13 = 0;
            const float* ap = sact + rc * 4;
#pragma unroll
            for (int i = 0; i < 80; ++i) {
                int row = i * 16 + rc;
                const float* wsrc = (i < 16)
                    ? (Wx_c + (size_t)row * 2048 + wcC)
                    : (i < 48) ? (Wh_c + (size_t)(row - 256) * 2048 + wcC)
                               : (Wm_c + (size_t)(row - 768) * 2048 + wcC);
                float2 w = *(const float2*)wsrc;
                float4 av = *(const float4*)(ap + i * 64);
                a00 = fmaf(w.x, av.x, a00); a01 = fmaf(w.x, av.y, a01);
                a02 = fmaf(w.x, av.z, a02); a03 = fmaf(w.x, av.w, a03);
                a10 = fmaf(w.y, av.x, a10); a11 = fmaf(w.y, av.y, a11);
                a12 = fmaf(w.y, av.z, a12); a13 = fmaf(w.y, av.w, a13);
            }
            RED8(4); RED8(8); RED8(16); RED8(32);
            if (rc == 0) {
                sgt[0 * 64 + tc] = a00; sgt[0 * 64 + tc + 1] = a10;
                sgt[1 * 64 + tc] = a01; sgt[1 * 64 + tc + 1] = a11;
                sgt[2 * 64 + tc] = a02; sgt[2 * 64 + tc + 1] = a12;
                sgt[3 * 64 + tc] = a03; sgt[3 * 64 + tc + 1] = a13;
            }
            __syncthreads();
            if (tid < 64) {
                int bl = tid >> 4, hc = tid & 15;
                int gb = 4 * btC + bl;
                float g4[4];
#pragma unroll
                for (int g = 0; g < 4; ++g)
                    g4[g] = sgt[bl * 64 + g * 16 + hc] + b_c[g * 512 + ntC * 16 + hc];
                size_t cidx = (size_t)gb * 512 + ntC * 16 + hc;
                float cold = c_main[cidx];
                float cn = sigm(g4[1]) * cold + sigm(g4[0]) * tanhf(g4[2]);
                float hn = sigm(g4[3]) * tanhf(cn);
                c_main[cidx] = cn;
                stg(&hm_new[cidx], hn);
                out[(size_t)gb * S_ * H_ + (size_t)t * 512 + ntC * 16 + hc] = hn;
            }
        }
        gbar(bar, tid, wg, ++bn);
    }

    for (int i = wg * 512 + tid; i < B_ * H_; i += 131072)
        out[(size_t)B_ * S_ * H_ + i] = ldc(&h_main[i]);
}

extern "C" void kernel_launch(void* const* d_in, const int* in_sizes, int n_in,
                              void* d_out, int out_size, void* d_ws, size_t ws_size,
                              hipStream_t stream) {
    const int*   x      = (const int*)d_in[0];
    const int*   taskp  = (const int*)d_in[1];
    const float* embed  = (const float*)d_in[2];
    const float* Wx_t   = (const float*)d_in[3];
    const float* Wh_t   = (const float*)d_in[4];
    const float* b_t    = (const float*)d_in[5];
    const float* Ws_p1  = (const float*)d_in[6];
    const float* Ws_p2  = (const float*)d_in[7];
    const float* Us_w   = (const float*)d_in[8];
    const float* Wx_c   = (const float*)d_in[10];
    const float* Wh_c   = (const float*)d_in[11];
    const float* Wm_c   = (const float*)d_in[12];
    const float* b_c    = (const float*)d_in[13];
    float* out = (float*)d_out;

    float* ws = (float*)d_ws;
    float* emb_t   = ws;                                  // S*E*B   = 4,194,304 ([t][e][b])
    float* h_task  = emb_t   + (size_t)S_ * E_ * B_;      // 2*K*B*H =   229,376
    float* c_task  = h_task  + 2 * (size_t)K_ * B_ * H_;  // K*B*H   =   114,688
    float* h_main  = c_task  + (size_t)K_ * B_ * H_;      // 2*B*H   =    32,768
    float* c_main  = h_main  + 2 * (size_t)B_ * H_;       // B*H     =    16,384
    float* p2      = c_main  + (size_t)B_ * H_;           // B*H     =    16,384
    float* partial = p2      + (size_t)B_ * H_;           // K*32*32 =     7,168
    unsigned* bar  = (unsigned*)(partial + 7168);         // 2-level barrier state

    hipMemsetAsync(bar, 0, 4096, stream);

    void* args[] = { (void*)&x, (void*)&taskp, (void*)&embed,
                     (void*)&Wx_t, (void*)&Wh_t, (void*)&b_t,
                     (void*)&Ws_p1, (void*)&Ws_p2, (void*)&Us_w,
                     (void*)&Wx_c, (void*)&Wh_c, (void*)&Wm_c, (void*)&b_c,
                     (void*)&out,
                     (void*)&emb_t, (void*)&h_task, (void*)&c_task,
                     (void*)&h_main, (void*)&c_main, (void*)&p2, (void*)&partial,
                     (void*)&bar };
    hipLaunchCooperativeKernel((void*)fused_all, dim3(256), dim3(512), args, 0, stream);
}

// Round 12
// 49870.413 us; speedup vs baseline: 1.1223x; 1.0105x over previous
//
#include <hip/hip_runtime.h>

#define B_ 32
#define S_ 512
#define E_ 256
#define H_ 512
#define G_ 2048
#define K_ 7
#define SCOPE __HIP_MEMORY_SCOPE_AGENT

typedef float vf32 __attribute__((ext_vector_type(32)));

__device__ __forceinline__ float sigm(float x) { return 1.f / (1.f + expf(-x)); }

__device__ __forceinline__ float ldc(const float* p) {
    return __hip_atomic_load(p, __ATOMIC_RELAXED, SCOPE);
}
__device__ __forceinline__ void ld2c(const float* p, float& a, float& b) {
    unsigned long long v =
        __hip_atomic_load((const unsigned long long*)p, __ATOMIC_RELAXED, SCOPE);
    a = __builtin_bit_cast(float, (unsigned)v);
    b = __builtin_bit_cast(float, (unsigned)(v >> 32));
}
__device__ __forceinline__ void stg(float* p, float v) {
    __hip_atomic_store(p, v, __ATOMIC_RELAXED, SCOPE);
}

// 2-level monotonic grid barrier (validated round 9).
__device__ __forceinline__ void gbar(unsigned* bar, int tid, int wg, unsigned n) {
    __syncthreads();
    if (tid == 0) {
        int g = wg >> 5;
        unsigned* gcnt = bar + 64 + g * 32;
        unsigned* ggen = bar + 320 + g * 32;
        unsigned old = __hip_atomic_fetch_add(gcnt, 1u, __ATOMIC_RELAXED, SCOPE);
        if (old == n * 32u - 1u) {
            unsigned rold = __hip_atomic_fetch_add(bar, 1u, __ATOMIC_RELAXED, SCOPE);
            if (rold == n * 8u - 1u) {
                __hip_atomic_store(bar + 32, n, __ATOMIC_RELAXED, SCOPE);
            } else {
                while (__hip_atomic_load(bar + 32, __ATOMIC_RELAXED, SCOPE) < n)
                    __builtin_amdgcn_s_sleep(1);
            }
            __hip_atomic_store(ggen, n, __ATOMIC_RELAXED, SCOPE);
        } else {
            while (__hip_atomic_load(ggen, __ATOMIC_RELAXED, SCOPE) < n)
                __builtin_amdgcn_s_sleep(1);
        }
        asm volatile("" ::: "memory");
    }
    __syncthreads();
}

#define RED8(m) do { \
    a00 += __shfl_xor(a00, m, 64); a01 += __shfl_xor(a01, m, 64); \
    a02 += __shfl_xor(a02, m, 64); a03 += __shfl_xor(a03, m, 64); \
    a10 += __shfl_xor(a10, m, 64); a11 += __shfl_xor(a11, m, 64); \
    a12 += __shfl_xor(a12, m, 64); a13 += __shfl_xor(a13, m, 64); } while (0)

#define FMA16(V, OFF) \
    _Pragma("unroll") \
    for (int i = 0; i < 16; ++i) { \
        float4 av = *(const float4*)(ap + (i + OFF) * 576); \
        a00 = fmaf(V[2*i], av.x, a00); a01 = fmaf(V[2*i], av.y, a01); \
        a02 = fmaf(V[2*i], av.z, a02); a03 = fmaf(V[2*i], av.w, a03); \
        a10 = fmaf(V[2*i+1], av.x, a10); a11 = fmaf(V[2*i+1], av.y, a11); \
        a12 = fmaf(V[2*i+1], av.z, a12); a13 = fmaf(V[2*i+1], av.w, a13); \
    }

__global__ __launch_bounds__(512, 2) void fused_all(
        const int* __restrict__ x, const int* __restrict__ taskp,
        const float* __restrict__ embed,
        const float* __restrict__ Wx_t, const float* __restrict__ Wh_t,
        const float* __restrict__ b_t,
        const float* __restrict__ Ws_p1, const float* __restrict__ Ws_p2,
        const float* __restrict__ Us_w,
        const float* __restrict__ Wx_c, const float* __restrict__ Wh_c,
        const float* __restrict__ Wm_c, const float* __restrict__ b_c,
        float* __restrict__ out,
        float* __restrict__ emb_t,
        float* __restrict__ h_task, float* __restrict__ c_task,
        float* __restrict__ h_main, float* __restrict__ c_main,
        float* __restrict__ p2w, float* __restrict__ partial,
        unsigned* __restrict__ bar)
{
    __shared__ float sact[27648];   // A: [768][36]; B: [512][36]; C: [1280][4]
    __shared__ float smisc[2048];

    const int wg = blockIdx.x, tid = threadIdx.x;
    const int lane = tid & 63, wave = tid >> 6;
    const int task = taskp[0];
    unsigned bn = 0;

    // thread coords (A & C): column-pair cp (0..31), row-chunk rc (0..15)
    const int cp = wave * 4 + (lane & 3);
    const int rc = (lane >> 2) & 15;
    const int tc = 2 * cp;                 // tile col (even)

    // ---------------- prologue: zero state, emb gather+transpose ----------------
    for (int i = wg * 512 + tid; i < 393216; i += 131072)
        stg(&h_task[i], 0.f);  // h_task(2)+c_task+h_main(2)+c_main contiguous
    for (int w = wg * 2 + (tid >> 8); w < S_ * B_; w += 512) {
        int ts = w >> 5, b = w & 31;
        int tok = x[b * S_ + ts];
        stg(&emb_t[(size_t)ts * 8192 + (tid & 255) * 32 + b],
            embed[(size_t)tok * E_ + (tid & 255)]);
    }

    // ---------------- persistent register weights (SSA ext-vectors) ----------------
    const int kA = wg >> 5, ntA = wg & 31;
    const int wcA = ((tc >> 4) << 9) + ntA * 16 + (tc & 15);
    vf32 wa0, wa1, wa2, wb;
    if (wg < 224) {
        int kk = kA + (kA >= task);
        const float* Wx = Wx_t + (size_t)kk * 256 * 2048;
        const float* Wh = Wh_t + (size_t)kk * 512 * 2048;
#pragma unroll
        for (int i = 0; i < 16; ++i) {
            float2 w = *(const float2*)(Wx + (size_t)(i * 16 + rc) * 2048 + wcA);
            wa0[2 * i] = w.x; wa0[2 * i + 1] = w.y;
        }
#pragma unroll
        for (int i = 0; i < 16; ++i) {
            float2 w = *(const float2*)(Wh + (size_t)(i * 16 + rc) * 2048 + wcA);
            wa1[2 * i] = w.x; wa1[2 * i + 1] = w.y;
        }
#pragma unroll
        for (int i = 0; i < 16; ++i) {
            float2 w = *(const float2*)(Wh + (size_t)((i + 16) * 16 + rc) * 2048 + wcA);
            wa2[2 * i] = w.x; wa2[2 * i + 1] = w.y;
        }
    } else if (wg < 232) {
        int wcP = (wg - 224) * 64 + tc;
#pragma unroll
        for (int i = 0; i < 16; ++i) {
            float2 w = *(const float2*)(Ws_p2 + (size_t)(i * 16 + rc) * 512 + wcP);
            wa0[2 * i] = w.x; wa0[2 * i + 1] = w.y;
        }
#pragma unroll
        for (int i = 0; i < 16; ++i) {
            float2 w = *(const float2*)(Ws_p2 + (size_t)((i + 16) * 16 + rc) * 512 + wcP);
            wa1[2 * i] = w.x; wa1[2 * i + 1] = w.y;
        }
#pragma unroll
        for (int i = 0; i < 16; ++i) {
            float2 w = *(const float2*)(Ws_p2 + (size_t)((i + 32) * 16 + rc) * 512 + wcP);
            wa2[2 * i] = w.x; wa2[2 * i + 1] = w.y;
        }
    }
    const int cB = tid & 15, rcB = (tid >> 4) & 15, bhB = tid >> 8;
    if (wg < 224) {
        int colB = (wg & 31) * 16 + cB;
#pragma unroll
        for (int i = 0; i < 32; ++i)
            wb[i] = Ws_p1[(size_t)colB * 512 + i * 16 + rcB];
    }
    gbar(bar, tid, wg, ++bn);

    for (int t = 0; t < S_; ++t) {
        const int old = t & 1, nw = old ^ 1;
        float* ht_old = h_task + (size_t)old * K_ * B_ * H_;
        float* ht_new = h_task + (size_t)nw * K_ * B_ * H_;
        float* hm_old = h_main + (size_t)old * B_ * H_;
        float* hm_new = h_main + (size_t)nw * B_ * H_;

        // ================= Phase A: task gates+cell (wg<224) + p2 (224..231) =====
        if (wg < 232) {
            const bool istask = wg < 224;
            if (istask) {
                for (int j = 0; j < 8; ++j) {        // emb rows 0..255
                    int idx = tid + 512 * j;
                    int rho = idx >> 4, b2 = (idx & 15) << 1;
                    *(float2*)(sact + rho * 36 + b2) =
                        *(const float2*)(emb_t + (size_t)t * 8192 + rho * 32 + b2);
                }
                for (int j = 0; j < 16; ++j) {       // h rows 256..767
                    int idx = tid + 512 * j;
                    int b = idx & 31, rp = idx >> 5;
                    float va, vb;
                    ld2c(&ht_old[((size_t)kA * 32 + b) * 512 + 2 * rp], va, vb);
                    sact[(256 + 2 * rp) * 36 + b] = va;
                    sact[(257 + 2 * rp) * 36 + b] = vb;
                }
            } else {
                for (int j = 0; j < 16; ++j) {       // hm rows 0..511
                    int idx = tid + 512 * j;
                    int b = idx & 31, rp = idx >> 5;
                    float va, vb;
                    ld2c(&hm_old[(size_t)b * 512 + 2 * rp], va, vb);
                    sact[(2 * rp) * 36 + b] = va;
                    sact[(2 * rp + 1) * 36 + b] = vb;
                }
                for (int j = 0; j < 8; ++j) {        // emb rows 512..767
                    int idx = tid + 512 * j;
                    int rho = idx >> 4, b2 = (idx & 15) << 1;
                    *(float2*)(sact + (512 + rho) * 36 + b2) =
                        *(const float2*)(emb_t + (size_t)t * 8192 + rho * 32 + b2);
                }
            }
            __syncthreads();
            for (int bg = 0; bg < 8; ++bg) {
                float a00 = 0, a01 = 0, a02 = 0, a03 = 0;
                float a10 = 0, a11 = 0, a12 = 0, a13 = 0;
                const float* ap = sact + rc * 36 + 4 * bg;
                FMA16(wa0, 0)
                FMA16(wa1, 16)
                FMA16(wa2, 32)
                RED8(4); RED8(8); RED8(16); RED8(32);
                if (rc == 0) {
                    smisc[(4 * bg + 0) * 64 + tc] = a00; smisc[(4 * bg + 0) * 64 + tc + 1] = a10;
                    smisc[(4 * bg + 1) * 64 + tc] = a01; smisc[(4 * bg + 1) * 64 + tc + 1] = a11;
                    smisc[(4 * bg + 2) * 64 + tc] = a02; smisc[(4 * bg + 2) * 64 + tc + 1] = a12;
                    smisc[(4 * bg + 3) * 64 + tc] = a03; smisc[(4 * bg + 3) * 64 + tc + 1] = a13;
                }
            }
            __syncthreads();
            if (istask) {
                int kk = kA + (kA >= task);
                int b = tid >> 4, hc = tid & 15;
                const float* bb = b_t + kk * G_ + ntA * 16 + hc;
                float gi = smisc[b * 64 + hc]      + bb[0];
                float gf = smisc[b * 64 + 16 + hc] + bb[512];
                float gg = smisc[b * 64 + 32 + hc] + bb[1024];
                float go = smisc[b * 64 + 48 + hc] + bb[1536];
                size_t cidx = ((size_t)kA * 32 + b) * 512 + ntA * 16 + hc;
                float cold = c_task[cidx];
                float cn = sigm(gf) * cold + sigm(gi) * tanhf(gg);
                float hn = sigm(go) * tanhf(cn);
                c_task[cidx] = cn;
                stg(&ht_new[cidx], hn);
            } else {
                int pb = wg - 224;
                for (int j = 0; j < 4; ++j) {
                    int idx = tid + 512 * j;
                    int b = idx >> 6, col = idx & 63;
                    stg(&p2w[(size_t)b * 512 + pb * 64 + col], smisc[b * 64 + col]);
                }
            }
        }
        gbar(bar, tid, wg, ++bn);

        // ================= Phase B: attention partials (wg<224) =================
        if (wg < 224) {
            const int ktB = wg >> 5, itB = wg & 31;
            for (int j = 0; j < 16; ++j) {
                int idx = tid + 512 * j;
                int b = idx & 31, rp = idx >> 5;
                float va, vb;
                ld2c(&ht_new[((size_t)ktB * 32 + b) * 512 + 2 * rp], va, vb);
                sact[(2 * rp) * 36 + b] = va;
                sact[(2 * rp + 1) * 36 + b] = vb;
            }
            __syncthreads();
            for (int bg = 0; bg < 4; ++bg) {
                float c0 = 0, c1 = 0, c2 = 0, c3 = 0;
                const float* ap = sact + rcB * 36 + bhB * 16 + 4 * bg;
#pragma unroll
                for (int i = 0; i < 32; ++i) {
                    float4 av = *(const float4*)(ap + i * 576);
                    c0 = fmaf(wb[i], av.x, c0); c1 = fmaf(wb[i], av.y, c1);
                    c2 = fmaf(wb[i], av.z, c2); c3 = fmaf(wb[i], av.w, c3);
                }
                c0 += __shfl_xor(c0, 16, 64); c0 += __shfl_xor(c0, 32, 64);
                c1 += __shfl_xor(c1, 16, 64); c1 += __shfl_xor(c1, 32, 64);
                c2 += __shfl_xor(c2, 16, 64); c2 += __shfl_xor(c2, 32, 64);
                c3 += __shfl_xor(c3, 16, 64); c3 += __shfl_xor(c3, 32, 64);
                if ((rcB & 3) == 0) {
                    int pp = rcB >> 2;
                    int bb0 = bhB * 16 + bg * 4;
                    smisc[pp * 512 + (bb0 + 0) * 16 + cB] = c0;
                    smisc[pp * 512 + (bb0 + 1) * 16 + cB] = c1;
                    smisc[pp * 512 + (bb0 + 2) * 16 + cB] = c2;
                    smisc[pp * 512 + (bb0 + 3) * 16 + cB] = c3;
                }
            }
            __syncthreads();
            {
                int b = tid >> 4, c = tid & 15;
                float s = smisc[b * 16 + c] + smisc[512 + b * 16 + c]
                        + smisc[1024 + b * 16 + c] + smisc[1536 + b * 16 + c];
                s = tanhf(s + ldc(&p2w[(size_t)b * 512 + itB * 16 + c]))
                    * Us_w[itB * 16 + c];
                s += __shfl_xor(s, 1, 64); s += __shfl_xor(s, 2, 64);
                s += __shfl_xor(s, 4, 64); s += __shfl_xor(s, 8, 64);
                if (c == 0) stg(&partial[((size_t)ktB * 32 + itB) * 32 + b], s);
            }
        }
        gbar(bar, tid, wg, ++bn);

        // ================= Phase C: softmax + Rt + main gates + cell ============
        {
            // XCD-aware decode: sharers of one ntC weight slice have equal wg%8
            const int ntC = ((wg >> 6) << 3) + (wg & 7);
            const int btC = (wg >> 3) & 7;
            const int wcC = ((tc >> 4) << 9) + ntC * 16 + (tc & 15);
            float* ssi = smisc;
            float* sa  = smisc + 32;
            float* sgt = smisc + 64;
            if (tid < 28) {
                int kq = tid >> 2, b2 = tid & 3;
                float ssum = 0.f;
                for (int itq = 0; itq < 32; ++itq)
                    ssum += ldc(&partial[((size_t)kq * 32 + itq) * 32 + 4 * btC + b2]);
                ssi[b2 * 7 + kq] = ssum;
            }
            __syncthreads();
            if (tid < 4) {
                float mx = -1e30f;
                for (int kq = 0; kq < 7; ++kq) mx = fmaxf(mx, ssi[tid * 7 + kq]);
                float den = 0.f, e[7];
                for (int kq = 0; kq < 7; ++kq) { e[kq] = expf(ssi[tid * 7 + kq] - mx); den += e[kq]; }
                float rd = 1.f / den;
                for (int kq = 0; kq < 7; ++kq) sa[tid * 7 + kq] = e[kq] * rd;
            }
            if (tid < 256)                            // emb rows 0..255
                *(float4*)(sact + tid * 4) =
                    *(const float4*)(emb_t + (size_t)t * 8192 + tid * 32 + 4 * btC);
            for (int j = 0; j < 2; ++j) {             // hm rows 256..767
                int idx = tid + 512 * j;
                int bl = idx & 3, rp = idx >> 2;
                float va, vb;
                ld2c(&hm_old[(size_t)(4 * btC + bl) * 512 + 2 * rp], va, vb);
                sact[(256 + 2 * rp) * 4 + bl] = va;
                sact[(257 + 2 * rp) * 4 + bl] = vb;
            }
            __syncthreads();                          // sa ready
            for (int j = 0; j < 2; ++j) {             // Rt rows 768..1279
                int idx = tid + 512 * j;
                int bl = idx & 3, rp = idx >> 2;
                float v0 = 0.f, v1 = 0.f;
#pragma unroll
                for (int kq = 0; kq < 7; ++kq) {
                    float ha, hb;
                    ld2c(&ht_new[((size_t)kq * 32 + 4 * btC + bl) * 512 + 2 * rp], ha, hb);
                    float aq = sa[bl * 7 + kq];
                    v0 = fmaf(aq, ha, v0);
                    v1 = fmaf(aq, hb, v1);
                }
                sact[(768 + 2 * rp) * 4 + bl] = v0;
                sact[(769 + 2 * rp) * 4 + bl] = v1;
            }
            __syncthreads();
            float a00 = 0, a01 = 0, a02 = 0, a03 = 0;
            float a10 = 0, a11 = 0, a12 = 0, a13 = 0;
            const float* ap = sact + rc * 4;
#pragma unroll
            for (int i = 0; i < 80; ++i) {
                int row = i * 16 + rc;
                const float* wsrc = (i < 16)
                    ? (Wx_c + (size_t)row * 2048 + wcC)
                    : (i < 48) ? (Wh_c + (size_t)(row - 256) * 2048 + wcC)
                               : (Wm_c + (size_t)(row - 768) * 2048 + wcC);
                float2 w = *(const float2*)wsrc;
                float4 av = *(const float4*)(ap + i * 64);
                a00 = fmaf(w.x, av.x, a00); a01 = fmaf(w.x, av.y, a01);
                a02 = fmaf(w.x, av.z, a02); a03 = fmaf(w.x, av.w, a03);
                a10 = fmaf(w.y, av.x, a10); a11 = fmaf(w.y, av.y, a11);
                a12 = fmaf(w.y, av.z, a12); a13 = fmaf(w.y, av.w, a13);
            }
            RED8(4); RED8(8); RED8(16); RED8(32);
            if (rc == 0) {
                sgt[0 * 64 + tc] = a00; sgt[0 * 64 + tc + 1] = a10;
                sgt[1 * 64 + tc] = a01; sgt[1 * 64 + tc + 1] = a11;
                sgt[2 * 64 + tc] = a02; sgt[2 * 64 + tc + 1] = a12;
                sgt[3 * 64 + tc] = a03; sgt[3 * 64 + tc + 1] = a13;
            }
            __syncthreads();
            if (tid < 64) {
                int bl = tid >> 4, hc = tid & 15;
                int gb = 4 * btC + bl;
                float g4[4];
#pragma unroll
                for (int g = 0; g < 4; ++g)
                    g4[g] = sgt[bl * 64 + g * 16 + hc] + b_c[g * 512 + ntC * 16 + hc];
                size_t cidx = (size_t)gb * 512 + ntC * 16 + hc;
                float cold = c_main[cidx];
                float cn = sigm(g4[1]) * cold + sigm(g4[0]) * tanhf(g4[2]);
                float hn = sigm(g4[3]) * tanhf(cn);
                c_main[cidx] = cn;
                stg(&hm_new[cidx], hn);
                out[(size_t)gb * S_ * H_ + (size_t)t * 512 + ntC * 16 + hc] = hn;
            }
        }
        gbar(bar, tid, wg, ++bn);
    }

    for (int i = wg * 512 + tid; i < B_ * H_; i += 131072)
        out[(size_t)B_ * S_ * H_ + i] = ldc(&h_main[i]);
}

extern "C" void kernel_launch(void* const* d_in, const int* in_sizes, int n_in,
                              void* d_out, int out_size, void* d_ws, size_t ws_size,
                              hipStream_t stream) {
    const int*   x      = (const int*)d_in[0];
    const int*   taskp  = (const int*)d_in[1];
    const float* embed  = (const float*)d_in[2];
    const float* Wx_t   = (const float*)d_in[3];
    const float* Wh_t   = (const float*)d_in[4];
    const float* b_t    = (const float*)d_in[5];
    const float* Ws_p1  = (const float*)d_in[6];
    const float* Ws_p2  = (const float*)d_in[7];
    const float* Us_w   = (const float*)d_in[8];
    const float* Wx_c   = (const float*)d_in[10];
    const float* Wh_c   = (const float*)d_in[11];
    const float* Wm_c   = (const float*)d_in[12];
    const float* b_c    = (const float*)d_in[13];
    float* out = (float*)d_out;

    float* ws = (float*)d_ws;
    float* emb_t   = ws;                                  // S*E*B   = 4,194,304 ([t][e][b])
    float* h_task  = emb_t   + (size_t)S_ * E_ * B_;      // 2*K*B*H =   229,376
    float* c_task  = h_task  + 2 * (size_t)K_ * B_ * H_;  // K*B*H   =   114,688
    float* h_main  = c_task  + (size_t)K_ * B_ * H_;      // 2*B*H   =    32,768
    float* c_main  = h_main  + 2 * (size_t)B_ * H_;       // B*H     =    16,384
    float* p2      = c_main  + (size_t)B_ * H_;           // B*H     =    16,384
    float* partial = p2      + (size_t)B_ * H_;           // K*32*32 =     7,168
    unsigned* bar  = (unsigned*)(partial + 7168);         // 2-level barrier state

    hipMemsetAsync(bar, 0, 4096, stream);

    void* args[] = { (void*)&x, (void*)&taskp, (void*)&embed,
                     (void*)&Wx_t, (void*)&Wh_t, (void*)&b_t,
                     (void*)&Ws_p1, (void*)&Ws_p2, (void*)&Us_w,
                     (void*)&Wx_c, (void*)&Wh_c, (void*)&Wm_c, (void*)&b_c,
                     (void*)&out,
                     (void*)&emb_t, (void*)&h_task, (void*)&c_task,
                     (void*)&h_main, (void*)&c_main, (void*)&p2, (void*)&partial,
                     (void*)&bar };
    hipLaunchCooperativeKernel((void*)fused_all, dim3(256), dim3(512), args, 0, stream);
}